// Round 7
// baseline (70.601 us; speedup 1.0000x reference)
//
#include <hip/hip_runtime.h>
#include <hip/hip_cooperative_groups.h>

namespace cg = cooperative_groups;

#define BB 384   // batch
#define DD 128   // embedding dim
#define NI 3     // number of losses
#define SS 25    // seq len in target
#define APB 8    // anchors per block
#define BPI (BB / APB)         // 48 blocks per i
#define GRID (NI * BPI)        // 144 blocks total (well under co-residency cap)
#define PSTRIDE 64             // padded partial stride per i

// ---------------------------------------------------------------------------
// Single cooperative kernel.
// Per block = (i, 8 consecutive anchors). Each thread owns row t: loads it
// once, computes 8 dots against LDS-resident anchor rows. Anchor norms free
// (thread t==a_k publishes own-row norm). Block pre-sums its 8 anchors'
// (tot,cnt) into one partial slot; grid.sync(); block 0 reduces + writes out.
// ---------------------------------------------------------------------------
__global__ __launch_bounds__(384) void fused_kernel(
    const float* __restrict__ vr,          // [NI, BB, DD]
    const float* __restrict__ target,      // [BB, SS, NI]
    const int*   __restrict__ label_item,  // [BB]
    float* __restrict__ part_T,            // [NI * PSTRIDE]
    int*   __restrict__ part_C,            // [NI * PSTRIDE]
    float* __restrict__ out)               // [4]
{
    const int blk  = blockIdx.x;           // 0 .. GRID-1
    const int i    = blk / BPI;
    const int b    = blk % BPI;
    const int a0   = b * APB;
    const int t    = threadIdx.x;          // 0 .. 383
    const int lane = t & 63;
    const int wid  = t >> 6;               // 0 .. 5

    __shared__ float ax[APB * DD];         // 8 anchor raw rows (contiguous)
    __shared__ float aas[APB];             // ||x_{a_k}||^2
    __shared__ float dp_seg[APB][BB];      // per-wave positive-dist segments
    __shared__ int   wp[6][APB];           // per-wave positive counts
    __shared__ float labs2[BB];            // i=2 only
    __shared__ float rf[6];
    __shared__ int   ri[6];

    // anchor rows -> LDS: 8 consecutive rows = one contiguous 4KB span
    if (t < APB * DD / 4)
        ((float4*)ax)[t] =
            ((const float4*)(vr + ((size_t)i * BB + a0) * DD))[t];

    // classification per anchor
    bool isPos[APB], isNeg[APB];
    if (i < 2) {
        const int li_t = label_item[t];
        #pragma unroll
        for (int k = 0; k < APB; ++k) {
            const int li_a = label_item[a0 + k];   // uniform -> scalar load
            isPos[k] = (li_t == li_a) && (t != a0 + k);
            isNeg[k] = (li_t != li_a);
        }
    } else {
        float m = 0.0f;
        const float* tp = target + (size_t)t * (SS * NI) + 2;
        #pragma unroll
        for (int s = 0; s < SS; ++s) m += tp[s * NI];
        m *= (1.0f / (float)SS);
        labs2[t] = m;
        __syncthreads();
        #pragma unroll
        for (int k = 0; k < APB; ++k) {
            const float la = labs2[a0 + k];
            isPos[k] = (m == la) && (t != a0 + k);
            isNeg[k] = (m != la);
        }
    }

    // in-wave compaction ranks per anchor
    int rp[APB];
    const unsigned long long lowmask =
        (lane == 0) ? 0ull : (~0ull >> (64 - lane));
    #pragma unroll
    for (int k = 0; k < APB; ++k) {
        const unsigned long long mpk = __ballot(isPos[k]);
        rp[k] = __popcll(mpk & lowmask);
        if (lane == 0) wp[wid][k] = __popcll(mpk);
    }
    __syncthreads();                       // B1: ax, wp (and labs2) visible

    int Pany = 0;
    #pragma unroll
    for (int k = 0; k < APB; ++k) {
        #pragma unroll
        for (int w = 0; w < 6; ++w) Pany += wp[w][k];
    }

    if (Pany > 0) {                        // block-uniform (i=2 blocks skip a.s.)
        // 8 dots + own-row squared norm; row loaded once from global
        const float4* xb = (const float4*)(vr + ((size_t)i * BB + t) * DD);
        float ab[APB];
        #pragma unroll
        for (int k = 0; k < APB; ++k) ab[k] = 0.0f;
        float bb = 0.0f;
        for (int c = 0; c < DD / 4; ++c) {
            const float4 bv = xb[c];
            bb = fmaf(bv.x, bv.x, bb); bb = fmaf(bv.y, bv.y, bb);
            bb = fmaf(bv.z, bv.z, bb); bb = fmaf(bv.w, bv.w, bb);
            #pragma unroll
            for (int k = 0; k < APB; ++k) {
                const float4 av = ((const float4*)(ax + k * DD))[c];
                ab[k] = fmaf(av.x, bv.x, ab[k]);
                ab[k] = fmaf(av.y, bv.y, ab[k]);
                ab[k] = fmaf(av.z, bv.z, ab[k]);
                ab[k] = fmaf(av.w, bv.w, ab[k]);
            }
        }
        // anchor a_k IS row a_k: its thread publishes bb as the anchor norm
        if (t >= a0 && t < a0 + APB) aas[t - a0] = bb;
        __syncthreads();                   // B2: aas visible

        const float invb   = 1.0f / fmaxf(sqrtf(bb), 1e-12f);
        const float bbterm = bb * invb * invb;
        float d[APB];
        #pragma unroll
        for (int k = 0; k < APB; ++k) {
            const float aak  = aas[k];
            const float inva = 1.0f / fmaxf(sqrtf(aak), 1e-12f);
            const float d2   = aak * inva * inva + bbterm
                               - 2.0f * ab[k] * inva * invb;
            d[k] = sqrtf(fmaxf(d2, 0.0f));
            if (isPos[k]) dp_seg[k][(wid << 6) + rp[k]] = d[k];
        }
        __syncthreads();                   // B3: dp_seg visible

        // sweep: each negative thread loops over compacted positives, 8 anchors
        float tot = 0.0f;
        int   cnt = 0;
        #pragma unroll
        for (int k = 0; k < APB; ++k) {
            if (isNeg[k]) {
                const float dk = d[k];
                #pragma unroll
                for (int w = 0; w < 6; ++w) {
                    const int    Pw  = wp[w][k];
                    const float* seg = &dp_seg[k][w << 6];
                    #pragma unroll 4
                    for (int p = 0; p < Pw; ++p) {
                        const float term = 1.0f - (dk - seg[p]);
                        if (term > 0.0f && term < 1.0f) { cnt += 1; tot += term; }
                    }
                }
            }
        }
        #pragma unroll
        for (int off = 32; off > 0; off >>= 1) {
            tot += __shfl_down(tot, off, 64);
            cnt += __shfl_down(cnt, off, 64);
        }
        if (lane == 0) { rf[wid] = tot; ri[wid] = cnt; }
        __syncthreads();                   // B4
        if (t == 0) {
            float T = 0.0f; int C = 0;
            #pragma unroll
            for (int w = 0; w < 6; ++w) { T += rf[w]; C += ri[w]; }
            part_T[i * PSTRIDE + b] = T;
            part_C[i * PSTRIDE + b] = C;
        }
    } else {
        if (t == 0) { part_T[i * PSTRIDE + b] = 0.0f; part_C[i * PSTRIDE + b] = 0; }
    }

    // ---- grid-wide barrier (every block reaches this; no early returns) ----
    cg::this_grid().sync();

    // ---- block 0 finalizes: 3 losses x 48 partials ----
    if (blk == 0) {
        const int ii = t >> 7;             // 0..2 (128-thread group per loss)
        const int bb2 = t & 127;
        float T = (bb2 < BPI) ? part_T[ii * PSTRIDE + bb2] : 0.0f;
        int   C = (bb2 < BPI) ? part_C[ii * PSTRIDE + bb2] : 0;
        #pragma unroll
        for (int off = 32; off > 0; off >>= 1) {
            T += __shfl_down(T, off, 64);
            C += __shfl_down(C, off, 64);
        }
        __syncthreads();                   // reuse rf/ri safely
        if (lane == 0) { rf[wid] = T; ri[wid] = C; }
        __syncthreads();
        if (t == 0) {
            float lsum = 0.0f;
            #pragma unroll
            for (int j = 0; j < NI; ++j) {
                const float Tj = rf[2 * j] + rf[2 * j + 1];
                const int   Cj = ri[2 * j] + ri[2 * j + 1];
                const float lj = (Cj > 0) ? (Tj / (float)Cj) : 0.0f;
                out[1 + j] = lj;
                lsum += lj;
            }
            out[0] = lsum;
        }
    }
}

extern "C" void kernel_launch(void* const* d_in, const int* in_sizes, int n_in,
                              void* d_out, int out_size, void* d_ws, size_t ws_size,
                              hipStream_t stream) {
    const float* vr         = (const float*)d_in[1];
    const float* target     = (const float*)d_in[2];
    const int*   label_item = (const int*)d_in[4];
    float* out = (float*)d_out;

    float* part_T = (float*)d_ws;                  // NI*PSTRIDE floats
    int*   part_C = (int*)(part_T + NI * PSTRIDE); // NI*PSTRIDE ints

    void* args[] = { (void*)&vr, (void*)&target, (void*)&label_item,
                     (void*)&part_T, (void*)&part_C, (void*)&out };
    hipLaunchCooperativeKernel((const void*)fused_kernel,
                               dim3(GRID), dim3(384), args, 0, stream);
}

// Round 8
// 37.430 us; speedup vs baseline: 1.8862x; 1.8862x over previous
//
#include <hip/hip_runtime.h>

#define BB 384   // batch
#define DD 128   // embedding dim
#define NI 3     // number of losses
#define SS 25    // seq len in target
#define APB 8    // anchors per block
#define BPI (BB / APB)         // 48 blocks per i
#define GRID (NI * BPI)        // 144
#define PSTRIDE 64             // padded partial stride per i

// ---------------------------------------------------------------------------
// Kernel 1: per block = (i, 8 consecutive anchors). Each thread owns row t:
// loads it once, computes 8 dots against LDS-resident anchor rows. Anchor
// norms free (thread t==a_k publishes own-row norm). Block pre-sums its 8
// anchors' (tot,cnt) into one partial slot. Plain stores, no atomics/fences —
// kernel-boundary ordering synchronizes with the finalize kernel.
// ---------------------------------------------------------------------------
__global__ __launch_bounds__(384) void triplet_kernel(
    const float* __restrict__ vr,          // [NI, BB, DD]
    const float* __restrict__ target,      // [BB, SS, NI]
    const int*   __restrict__ label_item,  // [BB]
    float* __restrict__ part_T,            // [NI * PSTRIDE]
    int*   __restrict__ part_C)            // [NI * PSTRIDE]
{
    const int blk  = blockIdx.x;           // 0 .. GRID-1
    const int i    = blk / BPI;
    const int b    = blk % BPI;
    const int a0   = b * APB;
    const int t    = threadIdx.x;          // 0 .. 383
    const int lane = t & 63;
    const int wid  = t >> 6;               // 0 .. 5

    __shared__ float ax[APB * DD];         // 8 anchor raw rows (contiguous)
    __shared__ float aas[APB];             // ||x_{a_k}||^2
    __shared__ float dp_seg[APB][BB];      // per-wave positive-dist segments
    __shared__ int   wp[6][APB];           // per-wave positive counts
    __shared__ float labs2[BB];            // i=2 only
    __shared__ float rf[6];
    __shared__ int   ri[6];

    // anchor rows -> LDS: 8 consecutive rows = one contiguous 4KB span
    if (t < APB * DD / 4)
        ((float4*)ax)[t] =
            ((const float4*)(vr + ((size_t)i * BB + a0) * DD))[t];

    // classification per anchor
    bool isPos[APB], isNeg[APB];
    if (i < 2) {
        const int li_t = label_item[t];
        #pragma unroll
        for (int k = 0; k < APB; ++k) {
            const int li_a = label_item[a0 + k];   // uniform -> scalar load
            isPos[k] = (li_t == li_a) && (t != a0 + k);
            isNeg[k] = (li_t != li_a);
        }
    } else {
        float m = 0.0f;
        const float* tp = target + (size_t)t * (SS * NI) + 2;
        #pragma unroll
        for (int s = 0; s < SS; ++s) m += tp[s * NI];
        m *= (1.0f / (float)SS);
        labs2[t] = m;
        __syncthreads();
        #pragma unroll
        for (int k = 0; k < APB; ++k) {
            const float la = labs2[a0 + k];
            isPos[k] = (m == la) && (t != a0 + k);
            isNeg[k] = (m != la);
        }
    }

    // in-wave compaction ranks per anchor
    int rp[APB];
    const unsigned long long lowmask =
        (lane == 0) ? 0ull : (~0ull >> (64 - lane));
    #pragma unroll
    for (int k = 0; k < APB; ++k) {
        const unsigned long long mpk = __ballot(isPos[k]);
        rp[k] = __popcll(mpk & lowmask);
        if (lane == 0) wp[wid][k] = __popcll(mpk);
    }
    __syncthreads();                       // B1: ax, wp (and labs2) visible

    int Pany = 0;
    #pragma unroll
    for (int k = 0; k < APB; ++k) {
        #pragma unroll
        for (int w = 0; w < 6; ++w) Pany += wp[w][k];
    }
    if (Pany == 0) {                       // block-uniform (all i=2 blocks a.s.)
        if (t == 0) { part_T[i * PSTRIDE + b] = 0.0f; part_C[i * PSTRIDE + b] = 0; }
        return;
    }

    // 8 dots + own-row squared norm; row loaded once from global
    const float4* xb = (const float4*)(vr + ((size_t)i * BB + t) * DD);
    float ab[APB];
    #pragma unroll
    for (int k = 0; k < APB; ++k) ab[k] = 0.0f;
    float bb = 0.0f;
    for (int c = 0; c < DD / 4; ++c) {
        const float4 bv = xb[c];
        bb = fmaf(bv.x, bv.x, bb); bb = fmaf(bv.y, bv.y, bb);
        bb = fmaf(bv.z, bv.z, bb); bb = fmaf(bv.w, bv.w, bb);
        #pragma unroll
        for (int k = 0; k < APB; ++k) {
            const float4 av = ((const float4*)(ax + k * DD))[c];
            ab[k] = fmaf(av.x, bv.x, ab[k]);
            ab[k] = fmaf(av.y, bv.y, ab[k]);
            ab[k] = fmaf(av.z, bv.z, ab[k]);
            ab[k] = fmaf(av.w, bv.w, ab[k]);
        }
    }
    // anchor a_k IS row a_k: its thread publishes bb as the anchor norm
    if (t >= a0 && t < a0 + APB) aas[t - a0] = bb;
    __syncthreads();                       // B2: aas visible

    const float invb   = 1.0f / fmaxf(sqrtf(bb), 1e-12f);
    const float bbterm = bb * invb * invb;
    float d[APB];
    #pragma unroll
    for (int k = 0; k < APB; ++k) {
        const float aak  = aas[k];
        const float inva = 1.0f / fmaxf(sqrtf(aak), 1e-12f);
        const float d2   = aak * inva * inva + bbterm
                           - 2.0f * ab[k] * inva * invb;
        d[k] = sqrtf(fmaxf(d2, 0.0f));
        if (isPos[k]) dp_seg[k][(wid << 6) + rp[k]] = d[k];
    }
    __syncthreads();                       // B3: dp_seg visible

    // sweep: each negative thread loops over compacted positives, 8 anchors
    float tot = 0.0f;
    int   cnt = 0;
    #pragma unroll
    for (int k = 0; k < APB; ++k) {
        if (isNeg[k]) {
            const float dk = d[k];
            #pragma unroll
            for (int w = 0; w < 6; ++w) {
                const int    Pw  = wp[w][k];
                const float* seg = &dp_seg[k][w << 6];
                #pragma unroll 4
                for (int p = 0; p < Pw; ++p) {
                    const float term = 1.0f - (dk - seg[p]);
                    if (term > 0.0f && term < 1.0f) { cnt += 1; tot += term; }
                }
            }
        }
    }
    #pragma unroll
    for (int off = 32; off > 0; off >>= 1) {
        tot += __shfl_down(tot, off, 64);
        cnt += __shfl_down(cnt, off, 64);
    }
    if (lane == 0) { rf[wid] = tot; ri[wid] = cnt; }
    __syncthreads();                       // B4
    if (t == 0) {
        float T = 0.0f; int C = 0;
        #pragma unroll
        for (int w = 0; w < 6; ++w) { T += rf[w]; C += ri[w]; }
        part_T[i * PSTRIDE + b] = T;
        part_C[i * PSTRIDE + b] = C;
    }
}

// ---------------------------------------------------------------------------
// Kernel 2: 384 threads; 128-thread group per loss. 1 barrier, 4 outputs.
// ---------------------------------------------------------------------------
__global__ __launch_bounds__(384) void finalize_kernel(
    const float* __restrict__ part_T,
    const int*   __restrict__ part_C,
    float* __restrict__ out)
{
    const int t    = threadIdx.x;
    const int lane = t & 63;
    const int wid  = t >> 6;
    const int i    = t >> 7;       // 0..2
    const int b    = t & 127;
    __shared__ float rf[6];
    __shared__ int   ri[6];

    float T = (b < BPI) ? part_T[i * PSTRIDE + b] : 0.0f;
    int   C = (b < BPI) ? part_C[i * PSTRIDE + b] : 0;
    #pragma unroll
    for (int off = 32; off > 0; off >>= 1) {
        T += __shfl_down(T, off, 64);
        C += __shfl_down(C, off, 64);
    }
    if (lane == 0) { rf[wid] = T; ri[wid] = C; }
    __syncthreads();
    if (t == 0) {
        float lsum = 0.0f;
        #pragma unroll
        for (int j = 0; j < NI; ++j) {
            const float Tj = rf[2 * j] + rf[2 * j + 1];
            const int   Cj = ri[2 * j] + ri[2 * j + 1];
            const float lj = (Cj > 0) ? (Tj / (float)Cj) : 0.0f;
            out[1 + j] = lj;
            lsum += lj;
        }
        out[0] = lsum;
    }
}

extern "C" void kernel_launch(void* const* d_in, const int* in_sizes, int n_in,
                              void* d_out, int out_size, void* d_ws, size_t ws_size,
                              hipStream_t stream) {
    const float* vr         = (const float*)d_in[1];
    const float* target     = (const float*)d_in[2];
    const int*   label_item = (const int*)d_in[4];
    float* out = (float*)d_out;

    float* part_T = (float*)d_ws;                  // NI*PSTRIDE floats
    int*   part_C = (int*)(part_T + NI * PSTRIDE); // NI*PSTRIDE ints

    triplet_kernel<<<GRID, 384, 0, stream>>>(vr, target, label_item,
                                             part_T, part_C);
    finalize_kernel<<<1, 384, 0, stream>>>(part_T, part_C, out);
}

// Round 9
// 22.618 us; speedup vs baseline: 3.1214x; 1.6549x over previous
//
#include <hip/hip_runtime.h>

#define BB 384   // batch
#define DD 128   // embedding dim
#define NI 3     // number of losses
#define SS 25    // seq len in target
#define APB 4    // anchors per block (R6-proven: 288 blocks ~ 1.1/CU, concurrent)
#define BPI (BB / APB)         // 96 blocks per i
#define GRID (NI * BPI)        // 288
#define PSTRIDE 128            // padded partial stride per i

// ---------------------------------------------------------------------------
// Kernel 1: per block = (i, 4 consecutive anchors). Each thread owns row t:
// loads it once, computes 4 dots against LDS-resident anchor rows. Anchor
// norms free (thread t==a_k publishes own-row norm). Positives compacted into
// a DENSE per-anchor list (block-level offsets derived after the B1 barrier —
// no extra barrier). Block pre-sums 4 anchors' (tot,cnt) into one slot.
// ---------------------------------------------------------------------------
__global__ __launch_bounds__(384) void triplet_kernel(
    const float* __restrict__ vr,          // [NI, BB, DD]
    const float* __restrict__ target,      // [BB, SS, NI]
    const int*   __restrict__ label_item,  // [BB]
    float* __restrict__ part_T,            // [NI * PSTRIDE]
    int*   __restrict__ part_C)            // [NI * PSTRIDE]
{
    const int blk  = blockIdx.x;           // 0 .. GRID-1
    const int i    = blk / BPI;
    const int b    = blk % BPI;
    const int a0   = b * APB;
    const int t    = threadIdx.x;          // 0 .. 383
    const int lane = t & 63;
    const int wid  = t >> 6;               // 0 .. 5

    __shared__ float ax[APB * DD];         // 4 anchor raw rows (contiguous)
    __shared__ float aas[APB];             // ||x_{a_k}||^2
    __shared__ float dp_seg[APB][BB];      // dense positive-distance lists
    __shared__ int   wp[6][APB];           // per-wave positive counts
    __shared__ float labs2[BB];            // i=2 only
    __shared__ float rf[6];
    __shared__ int   ri[6];

    // anchor rows -> LDS: 4 consecutive rows = one contiguous 2KB span
    if (t < APB * DD / 4)
        ((float4*)ax)[t] =
            ((const float4*)(vr + ((size_t)i * BB + a0) * DD))[t];

    // classification per anchor
    bool isPos[APB], isNeg[APB];
    if (i < 2) {
        const int li_t = label_item[t];
        #pragma unroll
        for (int k = 0; k < APB; ++k) {
            const int li_a = label_item[a0 + k];   // uniform -> scalar load
            isPos[k] = (li_t == li_a) && (t != a0 + k);
            isNeg[k] = (li_t != li_a);
        }
    } else {
        float m = 0.0f;
        const float* tp = target + (size_t)t * (SS * NI) + 2;
        #pragma unroll
        for (int s = 0; s < SS; ++s) m += tp[s * NI];
        m *= (1.0f / (float)SS);
        labs2[t] = m;
        __syncthreads();
        #pragma unroll
        for (int k = 0; k < APB; ++k) {
            const float la = labs2[a0 + k];
            isPos[k] = (m == la) && (t != a0 + k);
            isNeg[k] = (m != la);
        }
    }

    // in-wave compaction ranks per anchor
    int rp[APB];
    const unsigned long long lowmask =
        (lane == 0) ? 0ull : (~0ull >> (64 - lane));
    #pragma unroll
    for (int k = 0; k < APB; ++k) {
        const unsigned long long mpk = __ballot(isPos[k]);
        rp[k] = __popcll(mpk & lowmask);
        if (lane == 0) wp[wid][k] = __popcll(mpk);
    }
    __syncthreads();                       // B1: ax, wp (and labs2) visible

    // block-level dense offsets + totals per anchor (registers, no barrier)
    int P[APB], posBase[APB];
    #pragma unroll
    for (int k = 0; k < APB; ++k) {
        P[k] = 0; posBase[k] = 0;
        #pragma unroll
        for (int w = 0; w < 6; ++w) {
            if (w < wid) posBase[k] += wp[w][k];
            P[k] += wp[w][k];
        }
    }
    const int Pany = P[0] + P[1] + P[2] + P[3];
    if (Pany == 0) {                       // block-uniform (all i=2 blocks a.s.)
        if (t == 0) { part_T[i * PSTRIDE + b] = 0.0f; part_C[i * PSTRIDE + b] = 0; }
        return;
    }

    // 4 dots + own-row squared norm; row loaded once from global
    const float4* xb = (const float4*)(vr + ((size_t)i * BB + t) * DD);
    float ab0 = 0.0f, ab1 = 0.0f, ab2 = 0.0f, ab3 = 0.0f, bb = 0.0f;
    #pragma unroll 4
    for (int c = 0; c < DD / 4; ++c) {
        const float4 bv  = xb[c];
        const float4 a0v = ((const float4*)(ax          ))[c];
        const float4 a1v = ((const float4*)(ax +     DD))[c];
        const float4 a2v = ((const float4*)(ax + 2 * DD))[c];
        const float4 a3v = ((const float4*)(ax + 3 * DD))[c];
        ab0 = fmaf(a0v.x, bv.x, ab0); ab0 = fmaf(a0v.y, bv.y, ab0);
        ab0 = fmaf(a0v.z, bv.z, ab0); ab0 = fmaf(a0v.w, bv.w, ab0);
        ab1 = fmaf(a1v.x, bv.x, ab1); ab1 = fmaf(a1v.y, bv.y, ab1);
        ab1 = fmaf(a1v.z, bv.z, ab1); ab1 = fmaf(a1v.w, bv.w, ab1);
        ab2 = fmaf(a2v.x, bv.x, ab2); ab2 = fmaf(a2v.y, bv.y, ab2);
        ab2 = fmaf(a2v.z, bv.z, ab2); ab2 = fmaf(a2v.w, bv.w, ab2);
        ab3 = fmaf(a3v.x, bv.x, ab3); ab3 = fmaf(a3v.y, bv.y, ab3);
        ab3 = fmaf(a3v.z, bv.z, ab3); ab3 = fmaf(a3v.w, bv.w, ab3);
        bb  = fmaf(bv.x,  bv.x, bb ); bb  = fmaf(bv.y,  bv.y, bb );
        bb  = fmaf(bv.z,  bv.z, bb ); bb  = fmaf(bv.w,  bv.w, bb );
    }
    // anchor a_k IS row a_k: its thread publishes bb as the anchor norm
    if (t >= a0 && t < a0 + APB) aas[t - a0] = bb;
    __syncthreads();                       // B2: aas visible

    // d^2 = 2 - 2*cos (normalized rows have unit norm; |err| ~1e-7 << thresh)
    const float invb = 1.0f / fmaxf(sqrtf(bb), 1e-12f);
    const float ab[APB] = { ab0, ab1, ab2, ab3 };
    float d[APB];
    #pragma unroll
    for (int k = 0; k < APB; ++k) {
        const float inva = 1.0f / fmaxf(sqrtf(aas[k]), 1e-12f);
        const float cosv = ab[k] * (inva * invb);
        d[k] = sqrtf(fmaxf(fmaf(-2.0f, cosv, 2.0f), 0.0f));
        if (isPos[k]) dp_seg[k][posBase[k] + rp[k]] = d[k];
    }
    __syncthreads();                       // B3: dp_seg visible

    // sweep: each negative thread scans the dense positive list per anchor
    float tot = 0.0f;
    int   cnt = 0;
    #pragma unroll
    for (int k = 0; k < APB; ++k) {
        if (isNeg[k]) {
            const float dk = d[k];
            const float* seg = dp_seg[k];
            const int    Pk  = P[k];
            #pragma unroll 4
            for (int p = 0; p < Pk; ++p) {
                const float term = 1.0f - (dk - seg[p]);   // 1 - (an - ap)
                if (term > 0.0f && term < 1.0f) { cnt += 1; tot += term; }
            }
        }
    }
    #pragma unroll
    for (int off = 32; off > 0; off >>= 1) {
        tot += __shfl_down(tot, off, 64);
        cnt += __shfl_down(cnt, off, 64);
    }
    if (lane == 0) { rf[wid] = tot; ri[wid] = cnt; }
    __syncthreads();                       // B4
    if (t == 0) {
        float T = 0.0f; int C = 0;
        #pragma unroll
        for (int w = 0; w < 6; ++w) { T += rf[w]; C += ri[w]; }
        part_T[i * PSTRIDE + b] = T;
        part_C[i * PSTRIDE + b] = C;
    }
}

// ---------------------------------------------------------------------------
// Kernel 2: 384 threads; 128-thread group per loss. 1 barrier, 4 outputs.
// ---------------------------------------------------------------------------
__global__ __launch_bounds__(384) void finalize_kernel(
    const float* __restrict__ part_T,
    const int*   __restrict__ part_C,
    float* __restrict__ out)
{
    const int t    = threadIdx.x;
    const int lane = t & 63;
    const int wid  = t >> 6;
    const int i    = t >> 7;       // 0..2
    const int b    = t & 127;
    __shared__ float rf[6];
    __shared__ int   ri[6];

    float T = (b < BPI) ? part_T[i * PSTRIDE + b] : 0.0f;
    int   C = (b < BPI) ? part_C[i * PSTRIDE + b] : 0;
    #pragma unroll
    for (int off = 32; off > 0; off >>= 1) {
        T += __shfl_down(T, off, 64);
        C += __shfl_down(C, off, 64);
    }
    if (lane == 0) { rf[wid] = T; ri[wid] = C; }
    __syncthreads();
    if (t == 0) {
        float lsum = 0.0f;
        #pragma unroll
        for (int j = 0; j < NI; ++j) {
            const float Tj = rf[2 * j] + rf[2 * j + 1];
            const int   Cj = ri[2 * j] + ri[2 * j + 1];
            const float lj = (Cj > 0) ? (Tj / (float)Cj) : 0.0f;
            out[1 + j] = lj;
            lsum += lj;
        }
        out[0] = lsum;
    }
}

extern "C" void kernel_launch(void* const* d_in, const int* in_sizes, int n_in,
                              void* d_out, int out_size, void* d_ws, size_t ws_size,
                              hipStream_t stream) {
    const float* vr         = (const float*)d_in[1];
    const float* target     = (const float*)d_in[2];
    const int*   label_item = (const int*)d_in[4];
    float* out = (float*)d_out;

    float* part_T = (float*)d_ws;                  // NI*PSTRIDE floats
    int*   part_C = (int*)(part_T + NI * PSTRIDE); // NI*PSTRIDE ints

    triplet_kernel<<<GRID, 384, 0, stream>>>(vr, target, label_item,
                                             part_T, part_C);
    finalize_kernel<<<1, 384, 0, stream>>>(part_T, part_C, out);
}

// Round 10
// 22.068 us; speedup vs baseline: 3.1992x; 1.0249x over previous
//
#include <hip/hip_runtime.h>

#define BB 384   // batch
#define DD 128   // embedding dim
#define NI 3     // number of losses
#define SS 25    // seq len in target
#define APB 4    // anchors per block (288 blocks ~ 1.1/CU, proven in R6/R9)
#define BPI (BB / APB)         // 96 blocks per i
#define GRID (NI * BPI)        // 288
#define PSTRIDE 128            // padded partial stride per i

// ---------------------------------------------------------------------------
// Kernel 1: per block = (i, 4 consecutive anchors). Anchor rows are read via
// a BLOCK-UNIFORM pointer -> compiler emits scalar loads (SGPRs), so the dot
// loop is v_fma(v, s, v) with no LDS traffic. Each thread owns row t, loads
// it once (float4), computes 4 dots. Anchor norms free (thread t==a_k
// publishes own-row norm). Positives compacted into dense per-anchor lists.
// Block pre-sums 4 anchors' (tot,cnt) into one partial slot; plain stores.
// ---------------------------------------------------------------------------
__global__ __launch_bounds__(384) void triplet_kernel(
    const float* __restrict__ vr,          // [NI, BB, DD]
    const float* __restrict__ target,      // [BB, SS, NI]
    const int*   __restrict__ label_item,  // [BB]
    float* __restrict__ part_T,            // [NI * PSTRIDE]
    int*   __restrict__ part_C)            // [NI * PSTRIDE]
{
    const int blk  = blockIdx.x;           // 0 .. GRID-1
    const int i    = blk / BPI;            // uniform (SGPR)
    const int b    = blk % BPI;
    const int a0   = b * APB;
    const int t    = threadIdx.x;          // 0 .. 383
    const int lane = t & 63;
    const int wid  = t >> 6;               // 0 .. 5

    __shared__ float aas[APB];             // ||x_{a_k}||^2
    __shared__ float dp_seg[APB][BB];      // dense positive-distance lists
    __shared__ int   wp[6][APB];           // per-wave positive counts
    __shared__ float labs2[BB];            // i=2 only
    __shared__ float rf[6];
    __shared__ int   ri[6];

    // block-uniform anchor base pointer (scalar loads in the dot loop)
    const float4* axp = (const float4*)(vr + ((size_t)i * BB + a0) * DD);

    // classification per anchor
    bool isPos[APB], isNeg[APB];
    if (i < 2) {
        const int li_t = label_item[t];
        #pragma unroll
        for (int k = 0; k < APB; ++k) {
            const int li_a = label_item[a0 + k];   // uniform -> scalar load
            isPos[k] = (li_t == li_a) && (t != a0 + k);
            isNeg[k] = (li_t != li_a);
        }
    } else {
        float m = 0.0f;
        const float* tp = target + (size_t)t * (SS * NI) + 2;
        #pragma unroll
        for (int s = 0; s < SS; ++s) m += tp[s * NI];
        m *= (1.0f / (float)SS);
        labs2[t] = m;
        __syncthreads();
        #pragma unroll
        for (int k = 0; k < APB; ++k) {
            const float la = labs2[a0 + k];
            isPos[k] = (m == la) && (t != a0 + k);
            isNeg[k] = (m != la);
        }
    }

    // in-wave compaction ranks per anchor
    int rp[APB];
    const unsigned long long lowmask =
        (lane == 0) ? 0ull : (~0ull >> (64 - lane));
    #pragma unroll
    for (int k = 0; k < APB; ++k) {
        const unsigned long long mpk = __ballot(isPos[k]);
        rp[k] = __popcll(mpk & lowmask);
        if (lane == 0) wp[wid][k] = __popcll(mpk);
    }
    __syncthreads();                       // B1: wp (and labs2) visible

    // block-level dense offsets + totals per anchor (registers, no barrier)
    int P[APB], posBase[APB];
    #pragma unroll
    for (int k = 0; k < APB; ++k) {
        P[k] = 0; posBase[k] = 0;
        #pragma unroll
        for (int w = 0; w < 6; ++w) {
            if (w < wid) posBase[k] += wp[w][k];
            P[k] += wp[w][k];
        }
    }
    const int Pany = P[0] + P[1] + P[2] + P[3];
    if (Pany == 0) {                       // block-uniform (all i=2 blocks a.s.)
        if (t == 0) { part_T[i * PSTRIDE + b] = 0.0f; part_C[i * PSTRIDE + b] = 0; }
        return;
    }

    // 4 dots + own-row squared norm; own row float4 (vector), anchors scalar
    const float4* xb = (const float4*)(vr + ((size_t)i * BB + t) * DD);
    float ab0 = 0.0f, ab1 = 0.0f, ab2 = 0.0f, ab3 = 0.0f, bb = 0.0f;
    #pragma unroll 4
    for (int c = 0; c < DD / 4; ++c) {
        const float4 bv  = xb[c];
        const float4 a0v = axp[c];                  // uniform -> SGPRs
        const float4 a1v = axp[(DD / 4) + c];
        const float4 a2v = axp[2 * (DD / 4) + c];
        const float4 a3v = axp[3 * (DD / 4) + c];
        ab0 = fmaf(a0v.x, bv.x, ab0); ab0 = fmaf(a0v.y, bv.y, ab0);
        ab0 = fmaf(a0v.z, bv.z, ab0); ab0 = fmaf(a0v.w, bv.w, ab0);
        ab1 = fmaf(a1v.x, bv.x, ab1); ab1 = fmaf(a1v.y, bv.y, ab1);
        ab1 = fmaf(a1v.z, bv.z, ab1); ab1 = fmaf(a1v.w, bv.w, ab1);
        ab2 = fmaf(a2v.x, bv.x, ab2); ab2 = fmaf(a2v.y, bv.y, ab2);
        ab2 = fmaf(a2v.z, bv.z, ab2); ab2 = fmaf(a2v.w, bv.w, ab2);
        ab3 = fmaf(a3v.x, bv.x, ab3); ab3 = fmaf(a3v.y, bv.y, ab3);
        ab3 = fmaf(a3v.z, bv.z, ab3); ab3 = fmaf(a3v.w, bv.w, ab3);
        bb  = fmaf(bv.x,  bv.x, bb ); bb  = fmaf(bv.y,  bv.y, bb );
        bb  = fmaf(bv.z,  bv.z, bb ); bb  = fmaf(bv.w,  bv.w, bb );
    }
    // anchor a_k IS row a_k: its thread publishes bb as the anchor norm
    if (t >= a0 && t < a0 + APB) aas[t - a0] = bb;
    __syncthreads();                       // B2: aas visible

    // d^2 = 2 - 2*cos (unit-norm rows; approx err ~1e-6 << 0.037 threshold)
    const float invb = rsqrtf(fmaxf(bb, 1e-24f));
    const float ab[APB] = { ab0, ab1, ab2, ab3 };
    float d[APB];
    #pragma unroll
    for (int k = 0; k < APB; ++k) {
        const float inva = rsqrtf(fmaxf(aas[k], 1e-24f));
        const float cosv = ab[k] * (inva * invb);
        d[k] = sqrtf(fmaxf(fmaf(-2.0f, cosv, 2.0f), 0.0f));
        if (isPos[k]) dp_seg[k][posBase[k] + rp[k]] = d[k];
    }
    __syncthreads();                       // B3: dp_seg visible

    // sweep: each negative thread scans the dense positive list per anchor
    float tot = 0.0f;
    int   cnt = 0;
    #pragma unroll
    for (int k = 0; k < APB; ++k) {
        if (isNeg[k]) {
            const float dk = d[k];
            const float* seg = dp_seg[k];
            const int    Pk  = P[k];
            #pragma unroll 4
            for (int p = 0; p < Pk; ++p) {
                const float term = 1.0f - (dk - seg[p]);   // 1 - (an - ap)
                if (term > 0.0f && term < 1.0f) { cnt += 1; tot += term; }
            }
        }
    }
    #pragma unroll
    for (int off = 32; off > 0; off >>= 1) {
        tot += __shfl_down(tot, off, 64);
        cnt += __shfl_down(cnt, off, 64);
    }
    if (lane == 0) { rf[wid] = tot; ri[wid] = cnt; }
    __syncthreads();                       // B4
    if (t == 0) {
        float T = 0.0f; int C = 0;
        #pragma unroll
        for (int w = 0; w < 6; ++w) { T += rf[w]; C += ri[w]; }
        part_T[i * PSTRIDE + b] = T;
        part_C[i * PSTRIDE + b] = C;
    }
}

// ---------------------------------------------------------------------------
// Kernel 2: 384 threads; 128-thread group per loss. 1 barrier, 4 outputs.
// ---------------------------------------------------------------------------
__global__ __launch_bounds__(384) void finalize_kernel(
    const float* __restrict__ part_T,
    const int*   __restrict__ part_C,
    float* __restrict__ out)
{
    const int t    = threadIdx.x;
    const int lane = t & 63;
    const int wid  = t >> 6;
    const int i    = t >> 7;       // 0..2
    const int b    = t & 127;
    __shared__ float rf[6];
    __shared__ int   ri[6];

    float T = (b < BPI) ? part_T[i * PSTRIDE + b] : 0.0f;
    int   C = (b < BPI) ? part_C[i * PSTRIDE + b] : 0;
    #pragma unroll
    for (int off = 32; off > 0; off >>= 1) {
        T += __shfl_down(T, off, 64);
        C += __shfl_down(C, off, 64);
    }
    if (lane == 0) { rf[wid] = T; ri[wid] = C; }
    __syncthreads();
    if (t == 0) {
        float lsum = 0.0f;
        #pragma unroll
        for (int j = 0; j < NI; ++j) {
            const float Tj = rf[2 * j] + rf[2 * j + 1];
            const int   Cj = ri[2 * j] + ri[2 * j + 1];
            const float lj = (Cj > 0) ? (Tj / (float)Cj) : 0.0f;
            out[1 + j] = lj;
            lsum += lj;
        }
        out[0] = lsum;
    }
}

extern "C" void kernel_launch(void* const* d_in, const int* in_sizes, int n_in,
                              void* d_out, int out_size, void* d_ws, size_t ws_size,
                              hipStream_t stream) {
    const float* vr         = (const float*)d_in[1];
    const float* target     = (const float*)d_in[2];
    const int*   label_item = (const int*)d_in[4];
    float* out = (float*)d_out;

    float* part_T = (float*)d_ws;                  // NI*PSTRIDE floats
    int*   part_C = (int*)(part_T + NI * PSTRIDE); // NI*PSTRIDE ints

    triplet_kernel<<<GRID, 384, 0, stream>>>(vr, target, label_item,
                                             part_T, part_C);
    finalize_kernel<<<1, 384, 0, stream>>>(part_T, part_C, out);
}